// Round 1
// baseline (145.148 us; speedup 1.0000x reference)
//
#include <hip/hip_runtime.h>
#include <math.h>

#define NCLS   16
#define TILE   32
#define DCHUNK 32

struct Ws {
    int   counts[NCLS];
    int   starts[NCLS];
    float classSum[NCLS];
};

// ---------------- Kernel 1: histogram + prefix + zero accumulators ----------
__global__ void setup_kernel(const int* __restrict__ gt, int V,
                             int* __restrict__ counts, int* __restrict__ starts,
                             float* __restrict__ classSum) {
    __shared__ int hist[NCLS];
    int t = threadIdx.x;
    if (t < NCLS) { hist[t] = 0; classSum[t] = 0.0f; }
    __syncthreads();
    for (int v = t; v < V; v += blockDim.x) {
        int c = gt[v];
        if (c >= 0 && c < NCLS) atomicAdd(&hist[c], 1);
    }
    __syncthreads();
    if (t == 0) {
        int acc = 0;
        for (int c = 0; c < NCLS; ++c) {
            counts[c] = hist[c];
            starts[c] = acc;
            acc += hist[c];
        }
    }
}

// ---------------- Kernel 2: per-class pairwise MMD kernel sums --------------
// predict/target layout: [C, V] (i.e. element (v, d) at ptr[d*V + v]).
// Class c pixels are contiguous: v in [start_c, start_c + n_c)  (gt sorted).
__global__ __launch_bounds__(256) void mmd_kernel(
    const float* __restrict__ predict, const float* __restrict__ target,
    int V, int D,
    const int* __restrict__ counts, const int* __restrict__ starts,
    float* __restrict__ classSum)
{
    const int cz = blockIdx.z;
    const int n = counts[cz];
    if (n <= 0) return;
    const int start  = starts[cz];
    const int ntiles = (n + TILE - 1) / TILE;

    __shared__ float sPr[TILE][DCHUNK + 1];  // predict rows   (i side)
    __shared__ float sTr[TILE][DCHUNK + 1];  // target  rows
    __shared__ float sPc[TILE][DCHUNK + 1];  // predict cols   (j side)
    __shared__ float sTc[TILE][DCHUNK + 1];  // target  cols
    __shared__ float red[256];

    const int t  = threadIdx.x;
    const int tx = t & 15;   // col group: handles cols 2*tx, 2*tx+1
    const int ty = t >> 4;   // row group: handles rows 2*ty, 2*ty+1

    const float invs[6] = {-0.25f, -0.1f, -0.05f, -0.025f, -0.0125f, -1.0f/120.0f};

    float total = 0.0f;

    for (int tib = blockIdx.x; tib < ntiles; tib += gridDim.x)
    for (int tjb = blockIdx.y; tjb < ntiles; tjb += gridDim.y) {
        const int i0 = tib * TILE;
        const int j0 = tjb * TILE;

        float dpp[2][2] = {{0.f,0.f},{0.f,0.f}};
        float dtt[2][2] = {{0.f,0.f},{0.f,0.f}};
        float dpt[2][2] = {{0.f,0.f},{0.f,0.f}};

        for (int dc = 0; dc < D; dc += DCHUNK) {
            __syncthreads();  // protect previous chunk's reads
            // stage 4 arrays of TILE x DCHUNK; 256 threads -> 16 elems each.
            // k = d*32 + r so consecutive threads read consecutive pixels.
            for (int k = t; k < TILE * DCHUNK; k += 256) {
                int d = k >> 5;
                int r = k & 31;
                int gi = start + min(i0 + r, n - 1);
                int gj = start + min(j0 + r, n - 1);
                long off = (long)(dc + d) * (long)V;
                sPr[r][d] = predict[off + gi];
                sTr[r][d] = target [off + gi];
                sPc[r][d] = predict[off + gj];
                sTc[r][d] = target [off + gj];
            }
            __syncthreads();

            #pragma unroll
            for (int d = 0; d < DCHUNK; ++d) {
                float pr0 = sPr[2*ty + 0][d], pr1 = sPr[2*ty + 1][d];
                float tr0 = sTr[2*ty + 0][d], tr1 = sTr[2*ty + 1][d];
                float pc0 = sPc[2*tx + 0][d], pc1 = sPc[2*tx + 1][d];
                float tc0 = sTc[2*tx + 0][d], tc1 = sTc[2*tx + 1][d];
                float x;
                x = pr0 - pc0; dpp[0][0] += x*x;  x = pr0 - pc1; dpp[0][1] += x*x;
                x = pr1 - pc0; dpp[1][0] += x*x;  x = pr1 - pc1; dpp[1][1] += x*x;
                x = tr0 - tc0; dtt[0][0] += x*x;  x = tr0 - tc1; dtt[0][1] += x*x;
                x = tr1 - tc0; dtt[1][0] += x*x;  x = tr1 - tc1; dtt[1][1] += x*x;
                x = pr0 - tc0; dpt[0][0] += x*x;  x = pr0 - tc1; dpt[0][1] += x*x;
                x = pr1 - tc0; dpt[1][0] += x*x;  x = pr1 - tc1; dpt[1][1] += x*x;
            }
        }

        // epilogue: 6-bandwidth RBF kernel sum for the 2x2 pair tile
        #pragma unroll
        for (int a = 0; a < 2; ++a) {
            #pragma unroll
            for (int b = 0; b < 2; ++b) {
                int ii = i0 + 2*ty + a;
                int jj = j0 + 2*tx + b;
                if (ii < n && jj < n) {
                    float s = 0.0f;
                    #pragma unroll
                    for (int w = 0; w < 6; ++w) {
                        s += __expf(invs[w] * dpp[a][b])
                           + __expf(invs[w] * dtt[a][b])
                           - 2.0f * __expf(invs[w] * dpt[a][b]);
                    }
                    total += s;
                }
            }
        }
    }

    // block reduction, one atomic per block
    __syncthreads();
    red[t] = total;
    __syncthreads();
    for (int s = 128; s > 0; s >>= 1) {
        if (t < s) red[t] += red[t + s];
        __syncthreads();
    }
    if (t == 0) atomicAdd(&classSum[cz], red[0]);
}

// ---------------- Kernel 3: finalize scalar loss ----------------------------
__global__ void finalize_kernel(const int* __restrict__ counts,
                                const float* __restrict__ classSum,
                                float* __restrict__ out) {
    if (threadIdx.x == 0) {
        float loss = 0.0f;
        int k = 0;
        for (int c = 0; c < NCLS; ++c) {
            int n = counts[c];
            if (n > 0) {
                ++k;
                float fn    = (float)n;
                float denom = fmaxf(2.0f * fn * fn, 1.0f);
                float l     = classSum[c] / denom;
                if (l > 0.0f) loss += sqrtf(l);
            }
        }
        out[0] = (k > 0) ? (loss / (float)k) : 0.0f;
    }
}

extern "C" void kernel_launch(void* const* d_in, const int* in_sizes, int n_in,
                              void* d_out, int out_size, void* d_ws, size_t ws_size,
                              hipStream_t stream) {
    const float* predict = (const float*)d_in[0];
    const float* target  = (const float*)d_in[1];
    const int*   gt      = (const int*)d_in[2];
    // d_in[3] = ignore_mask: all-True, unused by the reference math.

    const int V = in_sizes[2];        // B*H*W = 4096
    const int D = in_sizes[0] / V;    // C = 128

    Ws* ws = (Ws*)d_ws;

    setup_kernel<<<1, 256, 0, stream>>>(gt, V, ws->counts, ws->starts, ws->classSum);

    dim3 grid(8, 8, NCLS);
    mmd_kernel<<<grid, 256, 0, stream>>>(predict, target, V, D,
                                         ws->counts, ws->starts, ws->classSum);

    finalize_kernel<<<1, 64, 0, stream>>>(ws->counts, ws->classSum, (float*)d_out);
}

// Round 2
// 140.135 us; speedup vs baseline: 1.0358x; 1.0358x over previous
//
#include <hip/hip_runtime.h>
#include <math.h>

#define NCLS 16
#define TILE 32
#define PAD  36      // floats per LDS row: 144 B -> rows 16B-aligned (b128 reads), +4 bank shift
#define NB   2048

struct Ctl {
    int   counts[NCLS];
    int   starts[NCLS + 1];
    int   tpc[NCLS];          // tiles per class dimension = ceil(n/TILE)
    int   pairBase[NCLS + 1]; // prefix sum of tpc^2
    float classSum[NCLS];
};

// ---------------- Kernel 1: norms + class boundaries (no atomics) -----------
// gt is SORTED -> class boundaries via binary search; contiguous segments == classes.
__global__ void prep_kernel(const float* __restrict__ P, const float* __restrict__ T,
                            const int* __restrict__ gt, int V, int D,
                            Ctl* __restrict__ ctl,
                            float* __restrict__ normP, float* __restrict__ normT,
                            int nbNorm) {
    int b = blockIdx.x;
    if (b < nbNorm) {
        int v = b * 256 + threadIdx.x;
        if (v < V) {
            float np = 0.f, nt = 0.f;
            for (int d = 0; d < D; ++d) {
                float x = P[(long)d * V + v]; np += x * x;
                float y = T[(long)d * V + v]; nt += y * y;
            }
            normP[v] = np; normT[v] = nt;
        }
    } else {
        int t = threadIdx.x;
        if (t < NCLS) {
            // lower_bound of class id t in sorted gt
            int lo = 0, hi = V;
            while (lo < hi) {
                int mid = (lo + hi) >> 1;
                if (gt[mid] < t) lo = mid + 1; else hi = mid;
            }
            ctl->starts[t] = lo;
            ctl->classSum[t] = 0.0f;   // ws is poisoned 0xAA each replay
        }
        if (t == 0) ctl->starts[NCLS] = V;
        __syncthreads();
        if (t == 0) {
            int pb = 0;
            for (int c = 0; c < NCLS; ++c) {
                int n = ctl->starts[c + 1] - ctl->starts[c];
                ctl->counts[c] = n;
                int tp = (n + TILE - 1) / TILE;
                ctl->tpc[c] = tp;
                ctl->pairBase[c] = pb;
                pb += tp * tp;
            }
            ctl->pairBase[NCLS] = pb;
        }
    }
}

// ---------------- Kernel 2: balanced flat list of 32x32 pair tiles ----------
// dist(i,j) = n_i + n_j - 2<x_i,x_j>  (Gram form, same as reference numerics)
__global__ __launch_bounds__(256) void mmd_kernel(
    const float* __restrict__ P, const float* __restrict__ T,
    int V, int D, const Ctl* __restrict__ ctl,
    const float* __restrict__ normP, const float* __restrict__ normT,
    float* __restrict__ classSum)
{
    __shared__ float sPr[TILE][PAD], sTr[TILE][PAD];
    __shared__ float sPc[TILE][PAD], sTc[TILE][PAD];
    __shared__ float wsum[4];

    const int t  = threadIdx.x;
    const int tx = t & 15;   // cols 2*tx, 2*tx+1
    const int ty = t >> 4;   // rows 2*ty, 2*ty+1
    const int W  = ctl->pairBase[NCLS];

    const float invs[6] = {-0.25f, -0.1f, -0.05f, -0.025f, -0.0125f, -1.0f/120.0f};

    for (int w = blockIdx.x; w < W; w += gridDim.x) {
        // decode work item -> (class, ti, tj); uniform per block
        int c = 0;
        while (ctl->pairBase[c + 1] <= w) ++c;
        const int local = w - ctl->pairBase[c];
        const int tp    = ctl->tpc[c];
        const int ti    = local / tp;
        const int tj    = local - ti * tp;
        const int n     = ctl->counts[c];
        const int start = ctl->starts[c];
        const int i0    = ti * TILE;
        const int j0    = tj * TILE;

        float dpp[2][2] = {{0.f,0.f},{0.f,0.f}};
        float dtt[2][2] = {{0.f,0.f},{0.f,0.f}};
        float dpt[2][2] = {{0.f,0.f},{0.f,0.f}};

        for (int dc = 0; dc < D; dc += TILE) {
            __syncthreads();   // protect previous chunk's reads / wsum
            // stage: lanes -> consecutive pixels (coalesced global reads)
            for (int k = t; k < TILE * TILE; k += 256) {
                int r = k & (TILE - 1);
                int d = k >> 5;
                int gi = start + min(i0 + r, n - 1);
                int gj = start + min(j0 + r, n - 1);
                long off = (long)(dc + d) * (long)V;
                sPr[r][d] = P[off + gi];
                sTr[r][d] = T[off + gi];
                sPc[r][d] = P[off + gj];
                sTc[r][d] = T[off + gj];
            }
            __syncthreads();

            #pragma unroll
            for (int dg = 0; dg < TILE; dg += 4) {
                float4 pr0 = *(const float4*)&sPr[2*ty    ][dg];
                float4 pr1 = *(const float4*)&sPr[2*ty + 1][dg];
                float4 tr0 = *(const float4*)&sTr[2*ty    ][dg];
                float4 tr1 = *(const float4*)&sTr[2*ty + 1][dg];
                float4 pc0 = *(const float4*)&sPc[2*tx    ][dg];
                float4 pc1 = *(const float4*)&sPc[2*tx + 1][dg];
                float4 tc0 = *(const float4*)&sTc[2*tx    ][dg];
                float4 tc1 = *(const float4*)&sTc[2*tx + 1][dg];

                dpp[0][0] += pr0.x*pc0.x + pr0.y*pc0.y + pr0.z*pc0.z + pr0.w*pc0.w;
                dpp[0][1] += pr0.x*pc1.x + pr0.y*pc1.y + pr0.z*pc1.z + pr0.w*pc1.w;
                dpp[1][0] += pr1.x*pc0.x + pr1.y*pc0.y + pr1.z*pc0.z + pr1.w*pc0.w;
                dpp[1][1] += pr1.x*pc1.x + pr1.y*pc1.y + pr1.z*pc1.z + pr1.w*pc1.w;

                dtt[0][0] += tr0.x*tc0.x + tr0.y*tc0.y + tr0.z*tc0.z + tr0.w*tc0.w;
                dtt[0][1] += tr0.x*tc1.x + tr0.y*tc1.y + tr0.z*tc1.z + tr0.w*tc1.w;
                dtt[1][0] += tr1.x*tc0.x + tr1.y*tc0.y + tr1.z*tc0.z + tr1.w*tc0.w;
                dtt[1][1] += tr1.x*tc1.x + tr1.y*tc1.y + tr1.z*tc1.z + tr1.w*tc1.w;

                dpt[0][0] += pr0.x*tc0.x + pr0.y*tc0.y + pr0.z*tc0.z + pr0.w*tc0.w;
                dpt[0][1] += pr0.x*tc1.x + pr0.y*tc1.y + pr0.z*tc1.z + pr0.w*tc1.w;
                dpt[1][0] += pr1.x*tc0.x + pr1.y*tc0.y + pr1.z*tc0.z + pr1.w*tc0.w;
                dpt[1][1] += pr1.x*tc1.x + pr1.y*tc1.y + pr1.z*tc1.z + pr1.w*tc1.w;
            }
        }

        // epilogue: assemble distances via Gram form, 6-bandwidth RBF sum
        float total = 0.0f;
        #pragma unroll
        for (int a = 0; a < 2; ++a) {
            #pragma unroll
            for (int b2 = 0; b2 < 2; ++b2) {
                int ii = i0 + 2*ty + a;
                int jj = j0 + 2*tx + b2;
                if (ii < n && jj < n) {
                    float nPi = normP[start + ii], nTi = normT[start + ii];
                    float nPj = normP[start + jj], nTj = normT[start + jj];
                    float Dpp = nPi + nPj - 2.0f * dpp[a][b2];
                    float Dtt = nTi + nTj - 2.0f * dtt[a][b2];
                    float Dpt = nPi + nTj - 2.0f * dpt[a][b2];
                    #pragma unroll
                    for (int s = 0; s < 6; ++s) {
                        total += __expf(invs[s] * Dpp)
                               + __expf(invs[s] * Dtt)
                               - 2.0f * __expf(invs[s] * Dpt);
                    }
                }
            }
        }

        // wave shuffle reduce (width 64), then 4 wave leaders via LDS
        #pragma unroll
        for (int off = 32; off > 0; off >>= 1)
            total += __shfl_down(total, off, 64);
        if ((t & 63) == 0) wsum[t >> 6] = total;
        __syncthreads();
        if (t == 0)
            atomicAdd(&classSum[c], wsum[0] + wsum[1] + wsum[2] + wsum[3]);
    }
}

// ---------------- Kernel 3: finalize scalar loss ----------------------------
__global__ void finalize_kernel(const int* __restrict__ counts,
                                const float* __restrict__ classSum,
                                float* __restrict__ out) {
    if (threadIdx.x == 0) {
        float loss = 0.0f;
        int k = 0;
        for (int c = 0; c < NCLS; ++c) {
            int n = counts[c];
            if (n > 0) {
                ++k;
                float fn    = (float)n;
                float denom = fmaxf(2.0f * fn * fn, 1.0f);
                float l     = classSum[c] / denom;
                if (l > 0.0f) loss += sqrtf(l);
            }
        }
        out[0] = (k > 0) ? (loss / (float)k) : 0.0f;
    }
}

extern "C" void kernel_launch(void* const* d_in, const int* in_sizes, int n_in,
                              void* d_out, int out_size, void* d_ws, size_t ws_size,
                              hipStream_t stream) {
    const float* predict = (const float*)d_in[0];
    const float* target  = (const float*)d_in[1];
    const int*   gt      = (const int*)d_in[2];
    // d_in[3] = ignore_mask: all-True, unused by the reference math.

    const int V = in_sizes[2];        // B*H*W = 4096
    const int D = in_sizes[0] / V;    // C = 128

    Ctl* ctl = (Ctl*)d_ws;
    size_t normOff = (sizeof(Ctl) + 15) & ~(size_t)15;
    float* normP = (float*)((char*)d_ws + normOff);
    float* normT = normP + V;

    int nbNorm = (V + 255) / 256;
    prep_kernel<<<nbNorm + 1, 256, 0, stream>>>(predict, target, gt, V, D,
                                                ctl, normP, normT, nbNorm);

    mmd_kernel<<<NB, 256, 0, stream>>>(predict, target, V, D, ctl,
                                       normP, normT, ctl->classSum ? (float*)((char*)d_ws + offsetof(Ctl, classSum)) : nullptr);

    finalize_kernel<<<1, 64, 0, stream>>>(ctl->counts ? (int*)d_ws : nullptr,
                                          (float*)((char*)d_ws + offsetof(Ctl, classSum)),
                                          (float*)d_out);
}